// Round 1
// baseline (399.180 us; speedup 1.0000x reference)
//
#include <hip/hip_runtime.h>

#define NSTEP 5
#define NB    65536
#define NACT  16
#define NATOM 51
#define MAIN_BLOCKS 2048
#define THREADS 256

// --- probe: is `done` stored 1 byte/element (jax bool) or 4 bytes/element? ---
// Sample bytes at positions ≡ 1 (mod 4) spread over the first 64 KB.
// 1-byte bool layout: those bytes are iid 0/1 -> some nonzero (P(miss)=2^-64).
// int32 (or f32 0.0/1.0) layout: those bytes are always 0.
__global__ void detect_done_layout(const unsigned char* __restrict__ db,
                                   int* __restrict__ flag) {
    int t = threadIdx.x;                         // 64 threads, one wave
    unsigned char v = db[1024 * t + 1];          // max index 64513 < 65536
    unsigned long long m = __ballot(v != 0);
    if (t == 0) *flag = (m != 0ULL) ? 1 : 0;     // 1 => 1-byte bool layout
}

// One wave per batch element; lane = atom index (51 active lanes).
// td_err_b = -sum_j td[j] * ((u-b)*log_p[l] + (b-l)*log_p[u])  -- pure gather via shfl.
__global__ __launch_bounds__(THREADS)
void dist_td_main(const float* __restrict__ dist,
                  const float* __restrict__ next_n_dist,
                  const int*   __restrict__ action,
                  const int*   __restrict__ next_n_action,
                  const float* __restrict__ reward,
                  const unsigned char* __restrict__ done_raw,
                  const float* __restrict__ weight,
                  const float* __restrict__ gamma_p,
                  const float* __restrict__ vmin_p,
                  const float* __restrict__ vmax_p,
                  const int*   __restrict__ flag_p,
                  float* __restrict__ td_out,     // d_out + 1, length NB
                  float* __restrict__ partials)   // ws, length MAIN_BLOCKS
{
    const int lane = threadIdx.x & 63;
    const int wid  = threadIdx.x >> 6;
    const int wave = blockIdx.x * (THREADS / 64) + wid;
    const int nwaves = MAIN_BLOCKS * (THREADS / 64);

    const float gamma = gamma_p[0];
    const float vmin  = vmin_p[0];
    const float vmax  = vmax_p[0];
    const float dz    = (vmax - vmin) / (float)(NATOM - 1);
    const float inv_dz = 1.0f / dz;
    float g5 = gamma;
    #pragma unroll
    for (int i = 1; i < NSTEP; ++i) g5 *= gamma;
    const int bool_layout = *flag_p;

    const bool  act     = lane < NATOM;
    const float support = vmin + dz * (float)lane;

    float acc = 0.0f;   // lane-0 accumulator of td*w for the loss

    for (int b = wave; b < NB; b += nwaves) {
        const int bu = __builtin_amdgcn_readfirstlane(b);
        const int a  = action[bu];
        const int na = next_n_action[bu];

        float r = 0.0f, gf = 1.0f;
        #pragma unroll
        for (int t = 0; t < NSTEP; ++t) { r += gf * reward[t * NB + bu]; gf *= gamma; }

        float nd;
        if (bool_layout) nd = (done_raw[bu] != 0) ? 0.0f : 1.0f;
        else             nd = (((const int*)done_raw)[bu] != 0) ? 0.0f : 1.0f;
        const float w = weight[bu];

        float td = 0.0f, lp = 0.0f;
        if (act) {
            td = next_n_dist[(b * NACT + na) * NATOM + lane];
            lp = __logf(dist[(b * NACT + a) * NATOM + lane]);
        }

        float tz = r + nd * g5 * support;           // lanes >=51 clip to vmax; harmless
        tz = fminf(fmaxf(tz, vmin), vmax);
        const float bf = (tz - vmin) * inv_dz;
        int l = (int)floorf(bf);
        int u = (int)ceilf(bf);
        if (u > 0 && l == u) l -= 1;                // sequential fix, matches reference
        if (l < NATOM - 1 && l == u) u += 1;

        const float lp_l = __shfl(lp, l);
        const float lp_u = __shfl(lp, u);
        float contrib = act
            ? -td * (((float)u - bf) * lp_l + (bf - (float)l) * lp_u)
            : 0.0f;

        #pragma unroll
        for (int off = 32; off >= 1; off >>= 1)
            contrib += __shfl_xor(contrib, off);

        if (lane == 0) {
            td_out[b] = contrib;
            acc += contrib * w;
        }
    }

    __shared__ float s_acc[THREADS / 64];
    if (lane == 0) s_acc[wid] = acc;
    __syncthreads();
    if (threadIdx.x == 0) {
        float s = 0.0f;
        #pragma unroll
        for (int i = 0; i < THREADS / 64; ++i) s += s_acc[i];
        partials[blockIdx.x] = s;
    }
}

__global__ void reduce_loss(const float* __restrict__ partials,
                            float* __restrict__ loss) {
    __shared__ float s_acc[4];
    float v = 0.0f;
    for (int i = threadIdx.x; i < MAIN_BLOCKS; i += 256) v += partials[i];
    #pragma unroll
    for (int off = 32; off >= 1; off >>= 1) v += __shfl_xor(v, off);
    const int lane = threadIdx.x & 63, wid = threadIdx.x >> 6;
    if (lane == 0) s_acc[wid] = v;
    __syncthreads();
    if (threadIdx.x == 0)
        loss[0] = (s_acc[0] + s_acc[1] + s_acc[2] + s_acc[3]) * (1.0f / (float)NB);
}

extern "C" void kernel_launch(void* const* d_in, const int* in_sizes, int n_in,
                              void* d_out, int out_size, void* d_ws, size_t ws_size,
                              hipStream_t stream) {
    const float* dist    = (const float*)d_in[0];
    const float* nnd     = (const float*)d_in[1];
    const int*   act     = (const int*)d_in[2];
    const int*   nact    = (const int*)d_in[3];
    const float* reward  = (const float*)d_in[4];
    const unsigned char* done = (const unsigned char*)d_in[5];
    const float* weight  = (const float*)d_in[6];
    const float* gamma   = (const float*)d_in[7];
    const float* vmin    = (const float*)d_in[8];
    const float* vmax    = (const float*)d_in[9];
    float* out = (float*)d_out;

    int*   flag     = (int*)d_ws;
    float* partials = (float*)((char*)d_ws + 256);

    detect_done_layout<<<1, 64, 0, stream>>>(done, flag);
    dist_td_main<<<MAIN_BLOCKS, THREADS, 0, stream>>>(
        dist, nnd, act, nact, reward, done, weight, gamma, vmin, vmax,
        flag, out + 1, partials);
    reduce_loss<<<1, 256, 0, stream>>>(partials, out);
}

// Round 2
// 361.343 us; speedup vs baseline: 1.1047x; 1.1047x over previous
//
#include <hip/hip_runtime.h>

#define NSTEP 5
#define NB    65536
#define NACT  16
#define NATOM 51
#define THREADS 256
#define WPB (THREADS / 64)      // waves per block = 4
#define BPW 8                   // batch elements per wave
#define MAIN_BLOCKS (NB / (WPB * BPW))   // 2048 blocks -> 8192 waves x 8 batches

// --- probe: is `done` stored 1 byte/element (jax bool) or 4 bytes/element? ---
// Sample bytes at positions ≡ 1 (mod 4) spread over the first 64 KB.
// 1-byte bool layout: those bytes are iid 0/1 -> some nonzero (P(miss)=2^-64).
// int32 (or f32 0.0/1.0) layout: those bytes are always 0.
__global__ void detect_done_layout(const unsigned char* __restrict__ db,
                                   int* __restrict__ flag) {
    int t = threadIdx.x;                         // 64 threads, one wave
    unsigned char v = db[1024 * t + 1];          // max index 64513 < 65536
    unsigned long long m = __ballot(v != 0);
    if (t == 0) *flag = (m != 0ULL) ? 1 : 0;     // 1 => 1-byte bool layout
}

// One wave per 8 consecutive batch elements; lane = atom index (51 active).
// td_err_b = -sum_j td[j] * ((u-b)*log_p[l] + (b-l)*log_p[u])  -- gather via shfl.
// ILP-8: all scalar loads merge to s_load_dwordx8; 16 row gathers in flight.
__global__ __launch_bounds__(THREADS)
void dist_td_main(const float* __restrict__ dist,
                  const float* __restrict__ next_n_dist,
                  const int*   __restrict__ action,
                  const int*   __restrict__ next_n_action,
                  const float* __restrict__ reward,
                  const unsigned char* __restrict__ done_raw,
                  const float* __restrict__ weight,
                  const float* __restrict__ gamma_p,
                  const float* __restrict__ vmin_p,
                  const float* __restrict__ vmax_p,
                  const int*   __restrict__ flag_p,
                  float* __restrict__ td_out,     // d_out + 1, length NB
                  float* __restrict__ partials)   // ws, length MAIN_BLOCKS
{
    const int lane = threadIdx.x & 63;
    const int wid  = threadIdx.x >> 6;
    const int wave = blockIdx.x * WPB + wid;
    const int b0   = __builtin_amdgcn_readfirstlane(wave * BPW);

    const float gamma = gamma_p[0];
    const float vmin  = vmin_p[0];
    const float vmax  = vmax_p[0];
    const float dz     = (vmax - vmin) / (float)(NATOM - 1);
    const float inv_dz = 1.0f / dz;
    float g5 = gamma;
    #pragma unroll
    for (int i = 1; i < NSTEP; ++i) g5 *= gamma;
    const int bool_layout = *flag_p;

    const bool  act     = lane < NATOM;
    const float support = vmin + dz * (float)lane;

    int   a[BPW], na[BPW];
    float r[BPW], nd[BPW], w[BPW], td[BPW], lp[BPW];

    #pragma unroll
    for (int i = 0; i < BPW; ++i) {
        a[i]  = action[b0 + i];
        na[i] = next_n_action[b0 + i];
        w[i]  = weight[b0 + i];
        r[i]  = 0.0f;
    }
    {
        float gf = 1.0f;
        #pragma unroll
        for (int t = 0; t < NSTEP; ++t) {
            #pragma unroll
            for (int i = 0; i < BPW; ++i) r[i] += gf * reward[t * NB + b0 + i];
            gf *= gamma;
        }
    }
    if (bool_layout) {
        const unsigned char* p = done_raw + b0;   // b0 multiple of 8 -> aligned
        #pragma unroll
        for (int i = 0; i < BPW; ++i) nd[i] = p[i] ? 0.0f : 1.0f;
    } else {
        const int* p = (const int*)done_raw + b0;
        #pragma unroll
        for (int i = 0; i < BPW; ++i) nd[i] = p[i] ? 0.0f : 1.0f;
    }

    // 16 independent row gathers -> all in flight before first use
    #pragma unroll
    for (int i = 0; i < BPW; ++i) {
        td[i] = act ? next_n_dist[((b0 + i) * NACT + na[i]) * NATOM + lane] : 0.0f;
        lp[i] = act ? dist[((b0 + i) * NACT + a[i]) * NATOM + lane] : 1.0f;
    }
    #pragma unroll
    for (int i = 0; i < BPW; ++i) lp[i] = __logf(lp[i]);

    float myout = 0.0f, myloss = 0.0f;
    #pragma unroll
    for (int i = 0; i < BPW; ++i) {
        float tz = r[i] + nd[i] * g5 * support;     // lanes >=51: clipped below
        tz = fminf(fmaxf(tz, vmin), vmax);
        const float bf = (tz - vmin) * inv_dz;
        int l = (int)floorf(bf);
        int u = (int)ceilf(bf);
        if (u > 0 && l == u) l -= 1;                // sequential fix, matches reference
        if (l < NATOM - 1 && l == u) u += 1;

        const float lp_l = __shfl(lp[i], l);
        const float lp_u = __shfl(lp[i], u);
        float c = act
            ? -td[i] * (((float)u - bf) * lp_l + (bf - (float)l) * lp_u)
            : 0.0f;
        #pragma unroll
        for (int off = 32; off >= 1; off >>= 1) c += __shfl_xor(c, off);
        if (lane == i) { myout = c; myloss = c * w[i]; }   // batch i parked in lane i
    }
    if (lane < BPW) td_out[b0 + lane] = myout;              // one 32B coalesced store

    // sum myloss over lanes 0..7 (groups of 8)
    #pragma unroll
    for (int off = 4; off >= 1; off >>= 1) myloss += __shfl_xor(myloss, off);

    __shared__ float s_acc[WPB];
    if (lane == 0) s_acc[wid] = myloss;
    __syncthreads();
    if (threadIdx.x == 0)
        partials[blockIdx.x] = s_acc[0] + s_acc[1] + s_acc[2] + s_acc[3];
}

__global__ void reduce_loss(const float* __restrict__ partials,
                            float* __restrict__ loss) {
    __shared__ float s_acc[4];
    float v = 0.0f;
    for (int i = threadIdx.x; i < MAIN_BLOCKS; i += 256) v += partials[i];
    #pragma unroll
    for (int off = 32; off >= 1; off >>= 1) v += __shfl_xor(v, off);
    const int lane = threadIdx.x & 63, wid = threadIdx.x >> 6;
    if (lane == 0) s_acc[wid] = v;
    __syncthreads();
    if (threadIdx.x == 0)
        loss[0] = (s_acc[0] + s_acc[1] + s_acc[2] + s_acc[3]) * (1.0f / (float)NB);
}

extern "C" void kernel_launch(void* const* d_in, const int* in_sizes, int n_in,
                              void* d_out, int out_size, void* d_ws, size_t ws_size,
                              hipStream_t stream) {
    const float* dist    = (const float*)d_in[0];
    const float* nnd     = (const float*)d_in[1];
    const int*   act     = (const int*)d_in[2];
    const int*   nact    = (const int*)d_in[3];
    const float* reward  = (const float*)d_in[4];
    const unsigned char* done = (const unsigned char*)d_in[5];
    const float* weight  = (const float*)d_in[6];
    const float* gamma   = (const float*)d_in[7];
    const float* vmin    = (const float*)d_in[8];
    const float* vmax    = (const float*)d_in[9];
    float* out = (float*)d_out;

    int*   flag     = (int*)d_ws;
    float* partials = (float*)((char*)d_ws + 256);

    detect_done_layout<<<1, 64, 0, stream>>>(done, flag);
    dist_td_main<<<MAIN_BLOCKS, THREADS, 0, stream>>>(
        dist, nnd, act, nact, reward, done, weight, gamma, vmin, vmax,
        flag, out + 1, partials);
    reduce_loss<<<1, 256, 0, stream>>>(partials, out);
}

// Round 3
// 359.421 us; speedup vs baseline: 1.1106x; 1.0053x over previous
//
#include <hip/hip_runtime.h>

#define NSTEP 5
#define NB    65536
#define NACT  16
#define NATOM 51
#define THREADS 256
#define WPB (THREADS / 64)      // waves per block = 4
#define BPW 8                   // batch elements per wave
#define MAIN_BLOCKS (NB / (WPB * BPW))   // 2048 blocks -> 8192 waves x 8 batches

// One wave per 8 consecutive batch elements; lane = atom index (51 active).
// td_err_b = -sum_j td[j] * ((u-b)*log_p[l] + (b-l)*log_p[u])  -- gather via shfl.
// ILP-8: scalar loads merge to s_load_dwordxN; 16 row gathers in flight.
//
// done-layout probe (inlined, per wave): sample bytes at offsets ≡1 (mod 4)
// spread over the first 64 KB. jax-bool 1-byte layout -> iid 0/1 bytes, some
// nonzero (P miss = 2^-64). int32 0/1 layout -> those bytes are always 0.
// f32 0.0/1.0 layout -> byte 1 of each element is 0 -> int-interp also correct.
__global__ __launch_bounds__(THREADS)
void dist_td_main(const float* __restrict__ dist,
                  const float* __restrict__ next_n_dist,
                  const int*   __restrict__ action,
                  const int*   __restrict__ next_n_action,
                  const float* __restrict__ reward,
                  const unsigned char* __restrict__ done_raw,
                  const float* __restrict__ weight,
                  const float* __restrict__ gamma_p,
                  const float* __restrict__ vmin_p,
                  const float* __restrict__ vmax_p,
                  float* __restrict__ td_out,     // d_out + 1, length NB
                  float* __restrict__ partials)   // ws, length MAIN_BLOCKS
{
    const int lane = threadIdx.x & 63;
    const int wid  = threadIdx.x >> 6;
    const int wave = blockIdx.x * WPB + wid;
    const int b0   = __builtin_amdgcn_readfirstlane(wave * BPW);

    // inline layout probe (L1/L2-hot after first wave)
    const unsigned char pv = done_raw[1024 * lane + 1];   // max idx 64513 < 65536
    const int bool_layout = (__ballot(pv != 0) != 0ULL) ? 1 : 0;

    const float gamma = gamma_p[0];
    const float vmin  = vmin_p[0];
    const float vmax  = vmax_p[0];
    const float dz     = (vmax - vmin) / (float)(NATOM - 1);
    const float inv_dz = 1.0f / dz;
    float g5 = gamma;
    #pragma unroll
    for (int i = 1; i < NSTEP; ++i) g5 *= gamma;

    const bool  act     = lane < NATOM;
    const float support = vmin + dz * (float)lane;

    int   a[BPW], na[BPW];
    float r[BPW], nd[BPW], w[BPW], td[BPW], lp[BPW];

    #pragma unroll
    for (int i = 0; i < BPW; ++i) {
        a[i]  = action[b0 + i];
        na[i] = next_n_action[b0 + i];
        w[i]  = weight[b0 + i];
        r[i]  = 0.0f;
    }
    {
        float gf = 1.0f;
        #pragma unroll
        for (int t = 0; t < NSTEP; ++t) {
            #pragma unroll
            for (int i = 0; i < BPW; ++i) r[i] += gf * reward[t * NB + b0 + i];
            gf *= gamma;
        }
    }
    if (bool_layout) {
        const unsigned char* p = done_raw + b0;   // b0 multiple of 8 -> aligned
        #pragma unroll
        for (int i = 0; i < BPW; ++i) nd[i] = p[i] ? 0.0f : 1.0f;
    } else {
        const int* p = (const int*)done_raw + b0;
        #pragma unroll
        for (int i = 0; i < BPW; ++i) nd[i] = p[i] ? 0.0f : 1.0f;
    }

    // 16 independent row gathers -> all in flight before first use
    #pragma unroll
    for (int i = 0; i < BPW; ++i) {
        td[i] = act ? next_n_dist[((b0 + i) * NACT + na[i]) * NATOM + lane] : 0.0f;
        lp[i] = act ? dist[((b0 + i) * NACT + a[i]) * NATOM + lane] : 1.0f;
    }
    #pragma unroll
    for (int i = 0; i < BPW; ++i) lp[i] = __logf(lp[i]);

    float myout = 0.0f, myloss = 0.0f;
    #pragma unroll
    for (int i = 0; i < BPW; ++i) {
        float tz = r[i] + nd[i] * g5 * support;     // lanes >=51: clipped below
        tz = fminf(fmaxf(tz, vmin), vmax);
        const float bf = (tz - vmin) * inv_dz;
        int l = (int)floorf(bf);
        int u = (int)ceilf(bf);
        if (u > 0 && l == u) l -= 1;                // sequential fix, matches reference
        if (l < NATOM - 1 && l == u) u += 1;

        const float lp_l = __shfl(lp[i], l);
        const float lp_u = __shfl(lp[i], u);
        float c = act
            ? -td[i] * (((float)u - bf) * lp_l + (bf - (float)l) * lp_u)
            : 0.0f;
        #pragma unroll
        for (int off = 32; off >= 1; off >>= 1) c += __shfl_xor(c, off);
        if (lane == i) { myout = c; myloss = c * w[i]; }   // batch i parked in lane i
    }
    if (lane < BPW) td_out[b0 + lane] = myout;              // one 32B coalesced store

    // sum myloss over lanes 0..7 (groups of 8)
    #pragma unroll
    for (int off = 4; off >= 1; off >>= 1) myloss += __shfl_xor(myloss, off);

    __shared__ float s_acc[WPB];
    if (lane == 0) s_acc[wid] = myloss;
    __syncthreads();
    if (threadIdx.x == 0)
        partials[blockIdx.x] = s_acc[0] + s_acc[1] + s_acc[2] + s_acc[3];
}

__global__ void reduce_loss(const float* __restrict__ partials,
                            float* __restrict__ loss) {
    __shared__ float s_acc[4];
    float v = 0.0f;
    for (int i = threadIdx.x; i < MAIN_BLOCKS; i += 256) v += partials[i];
    #pragma unroll
    for (int off = 32; off >= 1; off >>= 1) v += __shfl_xor(v, off);
    const int lane = threadIdx.x & 63, wid = threadIdx.x >> 6;
    if (lane == 0) s_acc[wid] = v;
    __syncthreads();
    if (threadIdx.x == 0)
        loss[0] = (s_acc[0] + s_acc[1] + s_acc[2] + s_acc[3]) * (1.0f / (float)NB);
}

extern "C" void kernel_launch(void* const* d_in, const int* in_sizes, int n_in,
                              void* d_out, int out_size, void* d_ws, size_t ws_size,
                              hipStream_t stream) {
    const float* dist    = (const float*)d_in[0];
    const float* nnd     = (const float*)d_in[1];
    const int*   act     = (const int*)d_in[2];
    const int*   nact    = (const int*)d_in[3];
    const float* reward  = (const float*)d_in[4];
    const unsigned char* done = (const unsigned char*)d_in[5];
    const float* weight  = (const float*)d_in[6];
    const float* gamma   = (const float*)d_in[7];
    const float* vmin    = (const float*)d_in[8];
    const float* vmax    = (const float*)d_in[9];
    float* out = (float*)d_out;

    float* partials = (float*)d_ws;

    dist_td_main<<<MAIN_BLOCKS, THREADS, 0, stream>>>(
        dist, nnd, act, nact, reward, done, weight, gamma, vmin, vmax,
        out + 1, partials);
    reduce_loss<<<1, 256, 0, stream>>>(partials, out);
}